// Round 1
// baseline (403.503 us; speedup 1.0000x reference)
//
#include <hip/hip_runtime.h>
#include <stdint.h>

typedef unsigned short u16;
typedef __bf16 bf16x8 __attribute__((ext_vector_type(8)));
typedef float  f32x4  __attribute__((ext_vector_type(4)));

#define BB   8
#define CCH  256   // input channels C
#define NN   4096  // H*W
#define CKV  128   // Ck == Cv
#define COO  256   // Co

__device__ __forceinline__ u16 f2bf(float f) {
    __bf16 h = (__bf16)f;
    return __builtin_bit_cast(u16, h);
}
__device__ __forceinline__ unsigned int pk(u16 a, u16 b) {
    return (unsigned int)a | ((unsigned int)b << 16);
}

// ---------------------------------------------------------------------------
// Kernel 1: kq = w_kq@x + b_kq  (fp32, split into bf16 hi+lo, swizzled)
//           v  = w_v @x + b_v   (bf16, swizzled for PV B-fragments)
//
// kq swizzle (per batch, u16 elements):
//   el(k, n) = (n>>4)*2048 + (k>>3)*128 + (n&15)*8 + (k&7)
//   -> MFMA A/B frags read 16B at chunkbase + lane*16 (contiguous per wave)
// v swizzle (per batch):
//   el(vd, m) = (vd>>4)*(16*NN) + (m>>3)*128 + (vd&15)*8 + (m&7)
// ---------------------------------------------------------------------------
__global__ __launch_bounds__(512, 2) void kqv_kernel(
    const float* __restrict__ x,   const float* __restrict__ wkq,
    const float* __restrict__ bkq, const float* __restrict__ wv,
    const float* __restrict__ bv,
    u16* __restrict__ kqh, u16* __restrict__ kql, u16* __restrict__ vsw)
{
    __shared__ float xs[16][16];     // [c][n]
    __shared__ float wks[16][132];   // [c][k]  (transposed w_kq, padded)
    __shared__ float wvs[16][132];   // [c][vd]

    const int b  = blockIdx.x & 7;
    const int n0 = (blockIdx.x >> 3) << 4;
    const int t  = threadIdx.x;

    const int wk_k  = t >> 2;          // 0..127
    const int wk_cg = (t & 3) << 2;    // 0,4,8,12

    const bool is_kq = (t < 256);
    const int c_n  = t & 15;           // kq half: column
    const int koct = (t >> 4) & 15;    // kq half: k-octet
    const int uu   = t & 255;          // v half
    const int vdim = uu & 127;
    const int moct = (uu >> 7) & 1;

    float acc[8];
#pragma unroll
    for (int j = 0; j < 8; ++j) acc[j] = 0.f;

    for (int ci = 0; ci < 16; ++ci) {
        const int cc0 = ci << 4;
        __syncthreads();
        if (t < 256)
            xs[t >> 4][t & 15] = x[(b * CCH + cc0 + (t >> 4)) * NN + n0 + (t & 15)];
        {
            const float4 a = *(const float4*)&wkq[wk_k * CCH + cc0 + wk_cg];
            wks[wk_cg + 0][wk_k] = a.x; wks[wk_cg + 1][wk_k] = a.y;
            wks[wk_cg + 2][wk_k] = a.z; wks[wk_cg + 3][wk_k] = a.w;
            const float4 c = *(const float4*)&wv[wk_k * CCH + cc0 + wk_cg];
            wvs[wk_cg + 0][wk_k] = c.x; wvs[wk_cg + 1][wk_k] = c.y;
            wvs[wk_cg + 2][wk_k] = c.z; wvs[wk_cg + 3][wk_k] = c.w;
        }
        __syncthreads();
        if (is_kq) {
#pragma unroll
            for (int cc = 0; cc < 16; ++cc) {
                const float xv = xs[cc][c_n];
                const float4 w0 = *(const float4*)&wks[cc][koct * 8];
                const float4 w1 = *(const float4*)&wks[cc][koct * 8 + 4];
                acc[0] = fmaf(w0.x, xv, acc[0]); acc[1] = fmaf(w0.y, xv, acc[1]);
                acc[2] = fmaf(w0.z, xv, acc[2]); acc[3] = fmaf(w0.w, xv, acc[3]);
                acc[4] = fmaf(w1.x, xv, acc[4]); acc[5] = fmaf(w1.y, xv, acc[5]);
                acc[6] = fmaf(w1.z, xv, acc[6]); acc[7] = fmaf(w1.w, xv, acc[7]);
            }
        } else {
#pragma unroll
            for (int cc = 0; cc < 16; ++cc) {
                const float wvv = wvs[cc][vdim];
                const float4 x0 = *(const float4*)&xs[cc][moct * 8];
                const float4 x1 = *(const float4*)&xs[cc][moct * 8 + 4];
                acc[0] = fmaf(wvv, x0.x, acc[0]); acc[1] = fmaf(wvv, x0.y, acc[1]);
                acc[2] = fmaf(wvv, x0.z, acc[2]); acc[3] = fmaf(wvv, x0.w, acc[3]);
                acc[4] = fmaf(wvv, x1.x, acc[4]); acc[5] = fmaf(wvv, x1.y, acc[5]);
                acc[6] = fmaf(wvv, x1.z, acc[6]); acc[7] = fmaf(wvv, x1.w, acc[7]);
            }
        }
    }

    if (is_kq) {
        u16 h[8], l[8];
#pragma unroll
        for (int j = 0; j < 8; ++j) {
            const float val = acc[j] + bkq[koct * 8 + j];
            const u16 hb = f2bf(val);
            const float hf = (float)__builtin_bit_cast(__bf16, hb);
            h[j] = hb;
            l[j] = f2bf(val - hf);
        }
        const int chunk = b * 65536 + (n0 >> 4) * 256 + koct * 16 + c_n;
        ((uint4*)kqh)[chunk] = make_uint4(pk(h[0],h[1]), pk(h[2],h[3]), pk(h[4],h[5]), pk(h[6],h[7]));
        ((uint4*)kql)[chunk] = make_uint4(pk(l[0],l[1]), pk(l[2],l[3]), pk(l[4],l[5]), pk(l[6],l[7]));
    } else {
        u16 p[8];
#pragma unroll
        for (int j = 0; j < 8; ++j) p[j] = f2bf(acc[j] + bv[vdim]);
        const int chunk = b * 65536 + (vdim >> 4) * 8192 + ((n0 >> 3) + moct) * 16 + (vdim & 15);
        ((uint4*)vsw)[chunk] = make_uint4(pk(p[0],p[1]), pk(p[2],p[3]), pk(p[4],p[5]), pk(p[6],p[7]));
    }
}

// ---------------------------------------------------------------------------
// Kernel 2: flash attention. BM=128 (8 waves x 16 rows), BN=64, D=128.
// S = Qh*Kh^T + Qh*Kl^T + Ql*Kh^T  (fp32 acc), online softmax, O += P*V.
// ctx stored fp32 as [B, N, 128] (position-major).
// ---------------------------------------------------------------------------
__global__ __launch_bounds__(512, 2) void flash_kernel(
    const u16* __restrict__ kqh, const u16* __restrict__ kql,
    const u16* __restrict__ vsw, float* __restrict__ ctx)
{
    // LDS: [0,8192)=K_hi  [8192,16384)=K_lo  [16384,24576)=V  [24576,32768)=P (1K u16/wave)
    __shared__ u16 lds[32768];

    const int b    = blockIdx.x & 7;
    const int mt   = blockIdx.x >> 3;          // 0..31
    const int t    = threadIdx.x;
    const int wave = t >> 6;
    const int lane = t & 63;
    const int c_l  = lane & 15;
    const int qq   = lane >> 4;                // quad 0..3
    const int pbase = 24576 + wave * 1024;

    // Q fragments straight from swizzled global (A-layout contiguous reads)
    const bf16x8* kqh8 = (const bf16x8*)kqh + b * 65536;
    const bf16x8* kql8 = (const bf16x8*)kql + b * 65536;
    const int ct_q = mt * 8 + wave;
    bf16x8 qh[4], ql[4];
#pragma unroll
    for (int k = 0; k < 4; ++k) {
        qh[k] = kqh8[ct_q * 256 + k * 64 + lane];
        ql[k] = kql8[ct_q * 256 + k * 64 + lane];
    }

    f32x4 o[8];
#pragma unroll
    for (int i = 0; i < 8; ++i) o[i] = (f32x4){0.f, 0.f, 0.f, 0.f};
    float m_r[4], l_r[4];
#pragma unroll
    for (int r = 0; r < 4; ++r) { m_r[r] = -__builtin_inff(); l_r[r] = 0.f; }

    for (int it = 0; it < 64; ++it) {
        const int n0 = it * 64;
        __syncthreads();   // previous iteration's K/V reads complete
        // stage 48 KB: 48 chunks of 1 KB, 6 per wave, direct-to-LDS DMA
#pragma unroll
        for (int ch = 0; ch < 6; ++ch) {
            const int cidx = wave * 6 + ch;
            const u16* gsrc;
            u16* ldst;
            if (cidx < 16) {
                gsrc = kqh + b * 524288 + (n0 >> 4) * 2048 + cidx * 512 + lane * 8;
                ldst = &lds[cidx * 512];
            } else if (cidx < 32) {
                const int cc = cidx - 16;
                gsrc = kql + b * 524288 + (n0 >> 4) * 2048 + cc * 512 + lane * 8;
                ldst = &lds[8192 + cc * 512];
            } else {
                const int j = cidx - 32;         // 0..15: ctv = j>>1, half = j&1
                gsrc = vsw + b * 524288 + (j >> 1) * 65536 + (n0 >> 3) * 128 + (j & 1) * 512 + lane * 8;
                ldst = &lds[16384 + j * 512];
            }
            __builtin_amdgcn_global_load_lds(
                (const __attribute__((address_space(1))) uint32_t*)gsrc,
                (__attribute__((address_space(3))) uint32_t*)ldst, 16, 0, 0);
        }
        __syncthreads();

        // S = Q K^T with hi/lo correction
        f32x4 s[4];
#pragma unroll
        for (int ct = 0; ct < 4; ++ct) s[ct] = (f32x4){0.f, 0.f, 0.f, 0.f};
#pragma unroll
        for (int ct = 0; ct < 4; ++ct) {
#pragma unroll
            for (int k = 0; k < 4; ++k) {
                const bf16x8 bh = *(const bf16x8*)&lds[ct * 2048 + k * 512 + lane * 8];
                const bf16x8 bl = *(const bf16x8*)&lds[8192 + ct * 2048 + k * 512 + lane * 8];
                s[ct] = __builtin_amdgcn_mfma_f32_16x16x32_bf16(qh[k], bh, s[ct], 0, 0, 0);
                s[ct] = __builtin_amdgcn_mfma_f32_16x16x32_bf16(qh[k], bl, s[ct], 0, 0, 0);
                s[ct] = __builtin_amdgcn_mfma_f32_16x16x32_bf16(ql[k], bh, s[ct], 0, 0, 0);
            }
        }

        // online softmax (rows = qq*4+r; row spread across 16 lanes of this quad)
        float mx[4];
#pragma unroll
        for (int r = 0; r < 4; ++r)
            mx[r] = fmaxf(fmaxf(s[0][r], s[1][r]), fmaxf(s[2][r], s[3][r]));
#pragma unroll
        for (int off = 1; off < 16; off <<= 1) {
#pragma unroll
            for (int r = 0; r < 4; ++r)
                mx[r] = fmaxf(mx[r], __shfl_xor(mx[r], off, 64));
        }
        float al[4], ps[4];
#pragma unroll
        for (int r = 0; r < 4; ++r) {
            const float mn = fmaxf(m_r[r], mx[r]);
            al[r] = __expf(m_r[r] - mn);
            m_r[r] = mn;
            ps[r] = 0.f;
        }
        // P = exp(S - m), write to per-wave P-LDS in A-fragment chunk layout
#pragma unroll
        for (int ct = 0; ct < 4; ++ct) {
#pragma unroll
            for (int r = 0; r < 4; ++r) {
                const float p = __expf(s[ct][r] - m_r[r]);
                ps[r] += p;
                lds[pbase + (ct * 2 + (c_l >> 3)) * 128 + (qq * 4 + r) * 8 + (c_l & 7)] = f2bf(p);
            }
        }
#pragma unroll
        for (int r = 0; r < 4; ++r) l_r[r] = l_r[r] * al[r] + ps[r];
#pragma unroll
        for (int cv = 0; cv < 8; ++cv) {
#pragma unroll
            for (int r = 0; r < 4; ++r) o[cv][r] *= al[r];
        }

        // O += P V
        const bf16x8 ap0 = *(const bf16x8*)&lds[pbase + lane * 8];
        const bf16x8 ap1 = *(const bf16x8*)&lds[pbase + 512 + lane * 8];
#pragma unroll
        for (int cv = 0; cv < 8; ++cv) {
            const bf16x8 v0 = *(const bf16x8*)&lds[16384 + cv * 1024 + lane * 8];
            o[cv] = __builtin_amdgcn_mfma_f32_16x16x32_bf16(ap0, v0, o[cv], 0, 0, 0);
            const bf16x8 v1 = *(const bf16x8*)&lds[16384 + cv * 1024 + 512 + lane * 8];
            o[cv] = __builtin_amdgcn_mfma_f32_16x16x32_bf16(ap1, v1, o[cv], 0, 0, 0);
        }
    }

    // epilogue: reduce l across the 16 lanes of each quad, normalize, store ctx
#pragma unroll
    for (int off = 1; off < 16; off <<= 1) {
#pragma unroll
        for (int r = 0; r < 4; ++r) l_r[r] += __shfl_xor(l_r[r], off, 64);
    }
    float inv[4];
#pragma unroll
    for (int r = 0; r < 4; ++r) inv[r] = 1.f / l_r[r];
    const int row0 = mt * 128 + wave * 16 + qq * 4;
#pragma unroll
    for (int cv = 0; cv < 8; ++cv) {
#pragma unroll
        for (int r = 0; r < 4; ++r)
            ctx[(b * NN + row0 + r) * CKV + cv * 16 + c_l] = o[cv][r] * inv[r];
    }
}

// ---------------------------------------------------------------------------
// Kernel 3: out = w_o @ ctx + b_o, fp32. ctx is [B, N, 128]; out is [B, 256, N].
// ---------------------------------------------------------------------------
__global__ __launch_bounds__(512, 2) void out_kernel(
    const float* __restrict__ ctx, const float* __restrict__ wo,
    const float* __restrict__ bo, float* __restrict__ out)
{
    __shared__ float cs[16][16];     // [v][n]
    __shared__ float wos[16][260];   // [v][o]

    const int b  = blockIdx.x & 7;
    const int n0 = (blockIdx.x >> 3) << 4;
    const int t  = threadIdx.x;
    const int c_n  = t & 15;
    const int ooct = t >> 4;         // 0..31
    const int wo_o  = t >> 1;        // 0..255
    const int wo_vg = (t & 1) << 3;  // 0 or 8

    float acc[8];
#pragma unroll
    for (int j = 0; j < 8; ++j) acc[j] = 0.f;

    for (int vi = 0; vi < 8; ++vi) {
        const int v0 = vi << 4;
        __syncthreads();
        if (t < 256)
            cs[t & 15][t >> 4] = ctx[(b * NN + n0 + (t >> 4)) * CKV + v0 + (t & 15)];
        {
            const float4 a = *(const float4*)&wo[wo_o * CKV + v0 + wo_vg];
            const float4 c = *(const float4*)&wo[wo_o * CKV + v0 + wo_vg + 4];
            wos[wo_vg + 0][wo_o] = a.x; wos[wo_vg + 1][wo_o] = a.y;
            wos[wo_vg + 2][wo_o] = a.z; wos[wo_vg + 3][wo_o] = a.w;
            wos[wo_vg + 4][wo_o] = c.x; wos[wo_vg + 5][wo_o] = c.y;
            wos[wo_vg + 6][wo_o] = c.z; wos[wo_vg + 7][wo_o] = c.w;
        }
        __syncthreads();
#pragma unroll
        for (int v = 0; v < 16; ++v) {
            const float xv = cs[v][c_n];
            const float4 w0 = *(const float4*)&wos[v][ooct * 8];
            const float4 w1 = *(const float4*)&wos[v][ooct * 8 + 4];
            acc[0] = fmaf(w0.x, xv, acc[0]); acc[1] = fmaf(w0.y, xv, acc[1]);
            acc[2] = fmaf(w0.z, xv, acc[2]); acc[3] = fmaf(w0.w, xv, acc[3]);
            acc[4] = fmaf(w1.x, xv, acc[4]); acc[5] = fmaf(w1.y, xv, acc[5]);
            acc[6] = fmaf(w1.z, xv, acc[6]); acc[7] = fmaf(w1.w, xv, acc[7]);
        }
    }
#pragma unroll
    for (int j = 0; j < 8; ++j)
        out[(b * COO + ooct * 8 + j) * NN + n0 + c_n] = acc[j] + bo[ooct * 8 + j];
}

// ---------------------------------------------------------------------------
extern "C" void kernel_launch(void* const* d_in, const int* in_sizes, int n_in,
                              void* d_out, int out_size, void* d_ws, size_t ws_size,
                              hipStream_t stream) {
    const float* x    = (const float*)d_in[0];
    const float* w_kq = (const float*)d_in[1];
    const float* b_kq = (const float*)d_in[2];
    const float* w_v  = (const float*)d_in[3];
    const float* b_v  = (const float*)d_in[4];
    const float* w_o  = (const float*)d_in[5];
    const float* b_o  = (const float*)d_in[6];
    float* out = (float*)d_out;

    // workspace layout
    u16*   kqh = (u16*)d_ws;                                   // 8 MB
    u16*   kql = (u16*)((char*)d_ws + (8u << 20));             // 8 MB
    u16*   vsw = (u16*)((char*)d_ws + (16u << 20));            // 8 MB
    float* ctx = (float*)((char*)d_ws + (24u << 20));          // 16 MB

    kqv_kernel<<<dim3(BB * (NN / 16)), dim3(512), 0, stream>>>(
        x, w_kq, b_kq, w_v, b_v, kqh, kql, vsw);
    flash_kernel<<<dim3(BB * (NN / 128)), dim3(512), 0, stream>>>(
        kqh, kql, vsw, ctx);
    out_kernel<<<dim3(BB * (NN / 16)), dim3(512), 0, stream>>>(
        ctx, w_o, b_o, out);
}

// Round 2
// 251.290 us; speedup vs baseline: 1.6057x; 1.6057x over previous
//
#include <hip/hip_runtime.h>
#include <stdint.h>

typedef unsigned short u16;
typedef _Float16 half8 __attribute__((ext_vector_type(8)));
typedef float    f32x4 __attribute__((ext_vector_type(4)));

#define NN 4096
#define SCALE_S 1.2011224087f   // sqrt(log2(e)); kq scaled so S is in log2 domain

__device__ __forceinline__ u16 f2h(float f) {
    _Float16 h = (_Float16)f;
    return __builtin_bit_cast(u16, h);
}
__device__ __forceinline__ float h2f(u16 b) {
    return (float)__builtin_bit_cast(_Float16, b);
}
__device__ __forceinline__ void dma16(const u16* src, const u16* dst) {
    __builtin_amdgcn_global_load_lds(
        (const __attribute__((address_space(1))) uint32_t*)src,
        (__attribute__((address_space(3))) uint32_t*)dst, 16, 0, 0);
}

// Universal chunk16 layout for a matrix M[d][p] (d = K-dim, p = M/N-dim):
//   u16 idx = (p>>4)*(D*2) + (d>>3)*128 + (p&15)*8 + (d&7)
// -> every MFMA A/B fragment read and every global_load_lds stage is
//    "wave-uniform base + lane*16B", contiguous 1KB per 16p x 64d.

// ---------------------------------------------------------------------------
// Kernel 0: cast weights fp32 -> fp16 hi/lo in chunk16 layout.
//   wA = [w_kq ; w_v] stacked [256 m][256 c];  wo [256 m][128 c]
// ---------------------------------------------------------------------------
__global__ __launch_bounds__(512) void wcast_kernel(
    const float* __restrict__ wkq, const float* __restrict__ wv,
    const float* __restrict__ wo,
    u16* __restrict__ wAh, u16* __restrict__ wAl,
    u16* __restrict__ woh, u16* __restrict__ wol)
{
    const int t = blockIdx.x * 512 + threadIdx.x;
    if (t < 65536) {
        const int m = t >> 8, c = t & 255;
        const float val = (m < 128) ? wkq[m * 256 + c] : wv[(m - 128) * 256 + c];
        const int el = (m >> 4) * 4096 + (c >> 3) * 128 + (m & 15) * 8 + (c & 7);
        const u16 hb = f2h(val);
        wAh[el] = hb;
        wAl[el] = f2h(val - h2f(hb));
    } else {
        const int u = t - 65536;
        const int m = u >> 7, c = u & 127;
        const float val = wo[m * 128 + c];
        const int el = (m >> 4) * 2048 + (c >> 3) * 128 + (m & 15) * 8 + (c & 7);
        const u16 hb = f2h(val);
        woh[el] = hb;
        wol[el] = f2h(val - h2f(hb));
    }
}

// ---------------------------------------------------------------------------
// Kernel 1: [kq ; v] = wA @ x + bias, MFMA fp16, 3-term (Wh*Xh + Wl*Xh + Wh*Xl).
// x cast to fp16 hi/lo on the fly into LDS. kq scaled by SCALE_S, stored fp16
// chunk16 (d=channel, p=position). v stored fp16 chunk16 (d=position, p=vdim).
// Block: M=256 x N=128, K=256 over 8 k-iters. 8 waves, wave = 32m x 128n.
// ---------------------------------------------------------------------------
__global__ __launch_bounds__(512, 2) void kqv_kernel(
    const float* __restrict__ x,
    const u16* __restrict__ wAh, const u16* __restrict__ wAl,
    const float* __restrict__ bkq, const float* __restrict__ bv,
    u16* __restrict__ kqh, u16* __restrict__ vsw)
{
    // u16 idx: Ah [0,8192) Al [8192,16384) Bh [16384,+8*520) Bl [20544,+8*520)
    __shared__ u16 lds[24704];
    const int b  = blockIdx.x & 7;
    const int nb = blockIdx.x >> 3;
    const int n0 = nb << 7;
    const int t  = threadIdx.x;
    const int wave = t >> 6, lane = t & 63;
    const int qq = lane >> 4, c_l = lane & 15;
    const int cL  = t >> 4;           // 0..31 (x row within k-slice)
    const int nL0 = (t & 15) << 3;    // 0..120

    f32x4 acc[2][8];
#pragma unroll
    for (int i = 0; i < 2; ++i)
#pragma unroll
        for (int j = 0; j < 8; ++j) acc[i][j] = (f32x4){0.f, 0.f, 0.f, 0.f};

    for (int ki = 0; ki < 8; ++ki) {
        __syncthreads();
        // stage A (weights) via DMA: 32 chunks of 1KB, 4/wave
#pragma unroll
        for (int ch = 0; ch < 4; ++ch) {
            const int cidx = wave * 4 + ch;
            if (cidx < 16)
                dma16(wAh + cidx * 4096 + ki * 512 + lane * 8, &lds[cidx * 512]);
            else
                dma16(wAl + (cidx - 16) * 4096 + ki * 512 + lane * 8,
                      &lds[8192 + (cidx - 16) * 512]);
        }
        // stage B (x) with on-the-fly fp16 hi/lo cast
        const float* xp = x + (size_t)((b * 256 + ki * 32 + cL) * NN) + n0 + nL0;
        const float4 xa = *(const float4*)xp;
        const float4 xb = *(const float4*)(xp + 4);
        const float vals[8] = {xa.x, xa.y, xa.z, xa.w, xb.x, xb.y, xb.z, xb.w};
        const int el0 = (nL0 >> 4) * 520 + (cL >> 3) * 128 + (nL0 & 15) * 8 + (cL & 7);
#pragma unroll
        for (int j = 0; j < 8; ++j) {
            const u16 hb = f2h(vals[j]);
            lds[16384 + el0 + 8 * j] = hb;
            lds[20544 + el0 + 8 * j] = f2h(vals[j] - h2f(hb));
        }
        __syncthreads();

        const half8 a0h = *(const half8*)&lds[(2 * wave) * 512 + lane * 8];
        const half8 a0l = *(const half8*)&lds[8192 + (2 * wave) * 512 + lane * 8];
        const half8 a1h = *(const half8*)&lds[(2 * wave + 1) * 512 + lane * 8];
        const half8 a1l = *(const half8*)&lds[8192 + (2 * wave + 1) * 512 + lane * 8];
#pragma unroll
        for (int tn = 0; tn < 8; ++tn) {
            const half8 bh = *(const half8*)&lds[16384 + tn * 520 + lane * 8];
            const half8 bl = *(const half8*)&lds[20544 + tn * 520 + lane * 8];
            acc[0][tn] = __builtin_amdgcn_mfma_f32_16x16x32_f16(a0h, bh, acc[0][tn], 0, 0, 0);
            acc[0][tn] = __builtin_amdgcn_mfma_f32_16x16x32_f16(a0l, bh, acc[0][tn], 0, 0, 0);
            acc[0][tn] = __builtin_amdgcn_mfma_f32_16x16x32_f16(a0h, bl, acc[0][tn], 0, 0, 0);
            acc[1][tn] = __builtin_amdgcn_mfma_f32_16x16x32_f16(a1h, bh, acc[1][tn], 0, 0, 0);
            acc[1][tn] = __builtin_amdgcn_mfma_f32_16x16x32_f16(a1l, bh, acc[1][tn], 0, 0, 0);
            acc[1][tn] = __builtin_amdgcn_mfma_f32_16x16x32_f16(a1h, bl, acc[1][tn], 0, 0, 0);
        }
    }

    // epilogue: rows 0..127 -> kq (biased, scaled), rows 128..255 -> v (biased)
#pragma unroll
    for (int T = 0; T < 2; ++T) {
        const int m0 = (2 * wave + T) * 16;
#pragma unroll
        for (int r = 0; r < 4; ++r) {
            const int m = m0 + qq * 4 + r;
            if (m < 128) {
                const float bias = bkq[m];
#pragma unroll
                for (int tn = 0; tn < 8; ++tn) {
                    const int n = n0 + tn * 16 + c_l;
                    const float val = (acc[T][tn][r] + bias) * SCALE_S;
                    kqh[b * 524288 + (n >> 4) * 2048 + (m >> 3) * 128 + (n & 15) * 8 + (m & 7)] = f2h(val);
                }
            } else {
                const int vd = m - 128;
                const float bias = bv[vd];
#pragma unroll
                for (int tn = 0; tn < 8; ++tn) {
                    const int n = n0 + tn * 16 + c_l;
                    vsw[b * 524288 + (vd >> 4) * 65536 + (n >> 3) * 128 + (vd & 15) * 8 + (n & 7)] = f2h(acc[T][tn][r] + bias);
                }
            }
        }
    }
}

// ---------------------------------------------------------------------------
// Kernel 2: flash attention, fp16, exp2 domain (kq pre-scaled).
// BM=128 (8 waves x 16 rows), BN=64, D=128. K double-buffered (DMA prefetch
// for it+1 overlaps compute of it); V single buffer DMA'd behind S-phase.
// ---------------------------------------------------------------------------
__global__ __launch_bounds__(512, 2) void flash_kernel(
    const u16* __restrict__ kqh, const u16* __restrict__ vsw,
    u16* __restrict__ ctxh)
{
    // u16 idx: K0 [0,8192) K1 [8192,16384) V [16384,24576) P [24576,32768)
    __shared__ u16 lds[32768];
    const int b  = blockIdx.x & 7;       // batch -> XCD affinity
    const int mt = blockIdx.x >> 3;      // 0..31 query tile
    const int t  = threadIdx.x;
    const int wave = t >> 6, lane = t & 63;
    const int qq = lane >> 4, c_l = lane & 15;
    const int pbase = 24576 + wave * 1024;
    const u16* kqb = kqh + b * 524288;
    const u16* vb  = vsw + b * 524288;

    // Q fragments direct from global (A-layout contiguous)
    half8 qh[4];
#pragma unroll
    for (int k = 0; k < 4; ++k)
        qh[k] = *(const half8*)(kqb + (mt * 8 + wave) * 2048 + k * 512 + lane * 8);

    f32x4 o[8];
#pragma unroll
    for (int i = 0; i < 8; ++i) o[i] = (f32x4){0.f, 0.f, 0.f, 0.f};
    float m_r[4], l_r[4];
#pragma unroll
    for (int r = 0; r < 4; ++r) { m_r[r] = -__builtin_inff(); l_r[r] = 0.f; }

    // pre-issue K(0) into K0
#pragma unroll
    for (int ch = 0; ch < 2; ++ch) {
        const int c = wave * 2 + ch;
        dma16(kqb + c * 512 + lane * 8, &lds[c * 512]);
    }

    for (int it = 0; it < 64; ++it) {
        const int n0 = it << 6;
        const int kcur = (it & 1) << 13;          // 0 or 8192
        __syncthreads();                          // barrier A: K(it) ready, V free
        // V(it) DMA — consumed after barrier B
#pragma unroll
        for (int ch = 0; ch < 2; ++ch) {
            const int j = wave * 2 + ch;
            dma16(vb + (j >> 1) * 65536 + (n0 >> 3) * 128 + (j & 1) * 512 + lane * 8,
                  &lds[16384 + j * 512]);
        }
        // K(it+1) prefetch into other buffer
        if (it < 63) {
            const int n1 = n0 + 64;
#pragma unroll
            for (int ch = 0; ch < 2; ++ch) {
                const int c = wave * 2 + ch;
                dma16(kqb + (n1 >> 4) * 2048 + c * 512 + lane * 8,
                      &lds[(kcur ^ 8192) + c * 512]);
            }
        }

        // S = Q K^T (scaled logits, log2 domain)
        f32x4 s[4];
#pragma unroll
        for (int ct = 0; ct < 4; ++ct) s[ct] = (f32x4){0.f, 0.f, 0.f, 0.f};
#pragma unroll
        for (int ct = 0; ct < 4; ++ct) {
#pragma unroll
            for (int k = 0; k < 4; ++k) {
                const half8 bh = *(const half8*)&lds[kcur + ct * 2048 + k * 512 + lane * 8];
                s[ct] = __builtin_amdgcn_mfma_f32_16x16x32_f16(qh[k], bh, s[ct], 0, 0, 0);
            }
        }

        // online softmax (base-2)
        float mx[4];
#pragma unroll
        for (int r = 0; r < 4; ++r)
            mx[r] = fmaxf(fmaxf(s[0][r], s[1][r]), fmaxf(s[2][r], s[3][r]));
#pragma unroll
        for (int off = 1; off < 16; off <<= 1) {
#pragma unroll
            for (int r = 0; r < 4; ++r)
                mx[r] = fmaxf(mx[r], __shfl_xor(mx[r], off, 64));
        }
        float al[4], ps[4];
#pragma unroll
        for (int r = 0; r < 4; ++r) {
            const float mn = fmaxf(m_r[r], mx[r]);
            al[r] = __builtin_amdgcn_exp2f(m_r[r] - mn);
            m_r[r] = mn;
            ps[r] = 0.f;
        }
#pragma unroll
        for (int ct = 0; ct < 4; ++ct) {
#pragma unroll
            for (int r = 0; r < 4; ++r) {
                const float p = __builtin_amdgcn_exp2f(s[ct][r] - m_r[r]);
                ps[r] += p;
                lds[pbase + (ct * 2 + (c_l >> 3)) * 128 + (qq * 4 + r) * 8 + (c_l & 7)] = f2h(p);
            }
        }
#pragma unroll
        for (int r = 0; r < 4; ++r) l_r[r] = l_r[r] * al[r] + ps[r];
#pragma unroll
        for (int cv = 0; cv < 8; ++cv) {
#pragma unroll
            for (int r = 0; r < 4; ++r) o[cv][r] *= al[r];
        }

        __syncthreads();                          // barrier B: V(it) ready
        // O += P V
        const half8 ap0 = *(const half8*)&lds[pbase + lane * 8];
        const half8 ap1 = *(const half8*)&lds[pbase + 512 + lane * 8];
#pragma unroll
        for (int cv = 0; cv < 8; ++cv) {
            const half8 v0 = *(const half8*)&lds[16384 + cv * 1024 + lane * 8];
            o[cv] = __builtin_amdgcn_mfma_f32_16x16x32_f16(ap0, v0, o[cv], 0, 0, 0);
            const half8 v1 = *(const half8*)&lds[16384 + cv * 1024 + 512 + lane * 8];
            o[cv] = __builtin_amdgcn_mfma_f32_16x16x32_f16(ap1, v1, o[cv], 0, 0, 0);
        }
    }

    // epilogue: reduce l over the quad's 16 lanes, normalize, store ctx fp16
#pragma unroll
    for (int off = 1; off < 16; off <<= 1) {
#pragma unroll
        for (int r = 0; r < 4; ++r) l_r[r] += __shfl_xor(l_r[r], off, 64);
    }
    float inv[4];
#pragma unroll
    for (int r = 0; r < 4; ++r) inv[r] = 1.f / l_r[r];
    u16* cb = ctxh + b * 524288 + (mt * 8 + wave) * 2048;
#pragma unroll
    for (int cv = 0; cv < 8; ++cv) {
#pragma unroll
        for (int r = 0; r < 4; ++r)
            cb[(cv * 2 + (c_l >> 3)) * 128 + (qq * 4 + r) * 8 + (c_l & 7)] =
                f2h(o[cv][r] * inv[r]);
    }
}

// ---------------------------------------------------------------------------
// Kernel 3: out = w_o @ ctx + b_o (fp32 out). MFMA fp16, 2-term (Wh+Wl)*Ch.
// Block: M=256 x N=128, K=128 over 4 k-iters.
// ---------------------------------------------------------------------------
__global__ __launch_bounds__(512, 2) void out_kernel(
    const u16* __restrict__ woh, const u16* __restrict__ wol,
    const u16* __restrict__ ctxh, const float* __restrict__ bo,
    float* __restrict__ out)
{
    // u16 idx: Ah [0,8192) Al [8192,16384) Bh [16384,20480)
    __shared__ u16 lds[20480];
    const int b  = blockIdx.x & 7;
    const int nb = blockIdx.x >> 3;
    const int n0 = nb << 7;
    const int t  = threadIdx.x;
    const int wave = t >> 6, lane = t & 63;
    const int qq = lane >> 4, c_l = lane & 15;

    f32x4 acc[2][8];
#pragma unroll
    for (int i = 0; i < 2; ++i)
#pragma unroll
        for (int j = 0; j < 8; ++j) acc[i][j] = (f32x4){0.f, 0.f, 0.f, 0.f};

    for (int ki = 0; ki < 4; ++ki) {
        __syncthreads();
#pragma unroll
        for (int ch = 0; ch < 5; ++ch) {
            const int cidx = wave * 5 + ch;      // 0..39
            if (cidx < 16)
                dma16(woh + cidx * 2048 + ki * 512 + lane * 8, &lds[cidx * 512]);
            else if (cidx < 32)
                dma16(wol + (cidx - 16) * 2048 + ki * 512 + lane * 8,
                      &lds[8192 + (cidx - 16) * 512]);
            else
                dma16(ctxh + b * 524288 + (nb * 8 + (cidx - 32)) * 2048 + ki * 512 + lane * 8,
                      &lds[16384 + (cidx - 32) * 512]);
        }
        __syncthreads();
        const half8 a0h = *(const half8*)&lds[(2 * wave) * 512 + lane * 8];
        const half8 a0l = *(const half8*)&lds[8192 + (2 * wave) * 512 + lane * 8];
        const half8 a1h = *(const half8*)&lds[(2 * wave + 1) * 512 + lane * 8];
        const half8 a1l = *(const half8*)&lds[8192 + (2 * wave + 1) * 512 + lane * 8];
#pragma unroll
        for (int tn = 0; tn < 8; ++tn) {
            const half8 bh = *(const half8*)&lds[16384 + tn * 512 + lane * 8];
            acc[0][tn] = __builtin_amdgcn_mfma_f32_16x16x32_f16(a0h, bh, acc[0][tn], 0, 0, 0);
            acc[0][tn] = __builtin_amdgcn_mfma_f32_16x16x32_f16(a0l, bh, acc[0][tn], 0, 0, 0);
            acc[1][tn] = __builtin_amdgcn_mfma_f32_16x16x32_f16(a1h, bh, acc[1][tn], 0, 0, 0);
            acc[1][tn] = __builtin_amdgcn_mfma_f32_16x16x32_f16(a1l, bh, acc[1][tn], 0, 0, 0);
        }
    }

#pragma unroll
    for (int T = 0; T < 2; ++T) {
        const int m0 = (2 * wave + T) * 16;
#pragma unroll
        for (int r = 0; r < 4; ++r) {
            const int m = m0 + qq * 4 + r;
            const float bias = bo[m];
#pragma unroll
            for (int tn = 0; tn < 8; ++tn)
                out[(size_t)((b * 256 + m) * NN) + n0 + tn * 16 + c_l] = acc[T][tn][r] + bias;
        }
    }
}

// ---------------------------------------------------------------------------
extern "C" void kernel_launch(void* const* d_in, const int* in_sizes, int n_in,
                              void* d_out, int out_size, void* d_ws, size_t ws_size,
                              hipStream_t stream) {
    const float* x    = (const float*)d_in[0];
    const float* w_kq = (const float*)d_in[1];
    const float* b_kq = (const float*)d_in[2];
    const float* w_v  = (const float*)d_in[3];
    const float* b_v  = (const float*)d_in[4];
    const float* w_o  = (const float*)d_in[5];
    const float* b_o  = (const float*)d_in[6];
    float* out = (float*)d_out;

    // workspace: kqh 8MB | vsw 8MB | ctxh 8MB | weights 384KB
    u16* kqh  = (u16*)d_ws;
    u16* vsw  = (u16*)((char*)d_ws + (8u << 20));
    u16* ctxh = (u16*)((char*)d_ws + (16u << 20));
    u16* wAh  = (u16*)((char*)d_ws + (24u << 20));
    u16* wAl  = wAh + 65536;
    u16* woh  = wAl + 65536;
    u16* wol  = woh + 32768;

    wcast_kernel<<<dim3(192), dim3(512), 0, stream>>>(w_kq, w_v, w_o, wAh, wAl, woh, wol);
    kqv_kernel<<<dim3(256), dim3(512), 0, stream>>>(x, wAh, wAl, b_kq, b_v, kqh, vsw);
    flash_kernel<<<dim3(256), dim3(512), 0, stream>>>(kqh, vsw, ctxh);
    out_kernel<<<dim3(256), dim3(512), 0, stream>>>(woh, wol, ctxh, b_o, out);
}

// Round 4
// 204.491 us; speedup vs baseline: 1.9732x; 1.2289x over previous
//
#include <hip/hip_runtime.h>
#include <stdint.h>

typedef unsigned short u16;
typedef _Float16 half8 __attribute__((ext_vector_type(8)));
typedef float    f32x4 __attribute__((ext_vector_type(4)));

#define NN 4096
#define SCALE_S 1.2011224087f   // sqrt(log2 e): applied to kq once -> logits in log2 domain

__device__ __forceinline__ u16 f2h(float f) {
    _Float16 h = (_Float16)f;
    return __builtin_bit_cast(u16, h);
}
__device__ __forceinline__ unsigned int pk(u16 a, u16 b) {
    return (unsigned int)a | ((unsigned int)b << 16);
}
__device__ __forceinline__ uint2 pk4h(float a, float b, float c, float d) {
    uint2 r; r.x = pk(f2h(a), f2h(b)); r.y = pk(f2h(c), f2h(d)); return r;
}
__device__ __forceinline__ void dma16(const u16* src, const u16* dst) {
    __builtin_amdgcn_global_load_lds(
        (const __attribute__((address_space(1))) uint32_t*)src,
        (__attribute__((address_space(3))) uint32_t*)dst, 16, 0, 0);
}

// chunk16 layout for M[d][p] (d = K-dim, inner-8): el = (p>>4)*(2*D) + (d>>3)*128 + (p&15)*8 + (d&7)
// -> MFMA A/B frag reads and DMA stages are all "uniform base + lane*16B".

// ---------------------------------------------------------------------------
// Kernel 0: weights fp32 -> fp16 chunk16. wA=[w_kq;w_v] [256 m][256 c]; wo [256][128].
// ---------------------------------------------------------------------------
__global__ __launch_bounds__(256) void wcast_kernel(
    const float* __restrict__ wkq, const float* __restrict__ wv,
    const float* __restrict__ wo, u16* __restrict__ wA, u16* __restrict__ woh)
{
    const int gid = blockIdx.x * 256 + threadIdx.x;   // 12288 total
    if (gid < 8192) {
        const int m = gid >> 5, co = gid & 31;
        const float* src = (m < 128) ? &wkq[m * 256 + co * 8] : &wv[(m - 128) * 256 + co * 8];
        u16 h[8];
#pragma unroll
        for (int i = 0; i < 8; ++i) h[i] = f2h(src[i]);
        *(uint4*)(wA + (m >> 4) * 4096 + co * 128 + (m & 15) * 8) =
            make_uint4(pk(h[0],h[1]), pk(h[2],h[3]), pk(h[4],h[5]), pk(h[6],h[7]));
    } else {
        const int u = gid - 8192;
        const int m = u >> 4, co = u & 15;
        const float* src = &wo[m * 128 + co * 8];
        u16 h[8];
#pragma unroll
        for (int i = 0; i < 8; ++i) h[i] = f2h(src[i]);
        *(uint4*)(woh + (m >> 4) * 2048 + co * 128 + (m & 15) * 8) =
            make_uint4(pk(h[0],h[1]), pk(h[2],h[3]), pk(h[4],h[5]), pk(h[6],h[7]));
    }
}

// ---------------------------------------------------------------------------
// Kernel 1: [kq ; v] = wA @ x + bias, single-term fp16 MFMA. x cast in-kernel.
// Block: M=256 x N=128 pos, K=256 over 4 iters of 64c. 8 waves:
//   waves 0-3: kq rows (A=w, B=x), C/D = kq[m][pos] -> kqh chunk16 [pos][c=m]
//   waves 4-7: v as x@wv^T (A=x, B=wv), C/D = v^T[pos][vd] -> vsw chunk16 [vd-p][n-d]
// ---------------------------------------------------------------------------
__global__ __launch_bounds__(512, 2) void kqv_kernel(
    const float* __restrict__ x, const u16* __restrict__ wA,
    const float* __restrict__ bkq, const float* __restrict__ bv,
    u16* __restrict__ kqh, u16* __restrict__ vsw)
{
    __shared__ __align__(16) u16 lds[24576];   // A(w) 16384 u16 | B(x) 8192 u16
    const int b  = blockIdx.x & 7;
    const int nb = blockIdx.x >> 3;
    const int n0 = nb << 7;
    const int t  = threadIdx.x;
    const int wave = t >> 6, lane = t & 63;
    const int qq = lane >> 4, c_l = lane & 15;

    f32x4 acc[2][8];
#pragma unroll
    for (int i = 0; i < 2; ++i)
#pragma unroll
        for (int j = 0; j < 8; ++j) acc[i][j] = (f32x4){0.f, 0.f, 0.f, 0.f};

    for (int ki = 0; ki < 4; ++ki) {
        __syncthreads();
        // stage A (weights c-slice, 32KB) via DMA: 32 chunks, 4/wave
#pragma unroll
        for (int ch = 0; ch < 4; ++ch) {
            const int c = wave * 4 + ch;
            dma16(wA + (c >> 1) * 4096 + ki * 1024 + (c & 1) * 512 + lane * 8,
                  &lds[c * 512]);
        }
        // stage B: x fp32 -> fp16 chunk16, 2 cells/thread (cell = 16B octet)
#pragma unroll
        for (int u = 0; u < 2; ++u) {
            const int cell = u * 512 + t;          // [0,1024)
            const int g = cell >> 7, oct = (cell >> 4) & 7, p16 = cell & 15;
            const int pos = n0 + g * 16 + p16;
            const float* xp = x + (size_t)((b * 256 + ki * 64 + oct * 8) * NN) + pos;
            u16 h[8];
#pragma unroll
            for (int i = 0; i < 8; ++i) h[i] = f2h(xp[(size_t)i * NN]);
            *(uint4*)&lds[16384 + g * 1024 + oct * 128 + p16 * 8] =
                make_uint4(pk(h[0],h[1]), pk(h[2],h[3]), pk(h[4],h[5]), pk(h[6],h[7]));
        }
        __syncthreads();

        if (wave < 4) {
#pragma unroll
            for (int ks = 0; ks < 2; ++ks) {
                const half8 a0 = *(const half8*)&lds[(2 * wave) * 1024 + ks * 512 + lane * 8];
                const half8 a1 = *(const half8*)&lds[(2 * wave + 1) * 1024 + ks * 512 + lane * 8];
#pragma unroll
                for (int tn = 0; tn < 8; ++tn) {
                    const half8 bf = *(const half8*)&lds[16384 + tn * 1024 + ks * 512 + lane * 8];
                    acc[0][tn] = __builtin_amdgcn_mfma_f32_16x16x32_f16(a0, bf, acc[0][tn], 0, 0, 0);
                    acc[1][tn] = __builtin_amdgcn_mfma_f32_16x16x32_f16(a1, bf, acc[1][tn], 0, 0, 0);
                }
            }
        } else {
            const int w4 = wave - 4;
#pragma unroll
            for (int ks = 0; ks < 2; ++ks) {
                const half8 a0 = *(const half8*)&lds[16384 + (2 * w4) * 1024 + ks * 512 + lane * 8];
                const half8 a1 = *(const half8*)&lds[16384 + (2 * w4 + 1) * 1024 + ks * 512 + lane * 8];
#pragma unroll
                for (int tn = 0; tn < 8; ++tn) {
                    const half8 bf = *(const half8*)&lds[(8 + tn) * 1024 + ks * 512 + lane * 8];
                    acc[0][tn] = __builtin_amdgcn_mfma_f32_16x16x32_f16(a0, bf, acc[0][tn], 0, 0, 0);
                    acc[1][tn] = __builtin_amdgcn_mfma_f32_16x16x32_f16(a1, bf, acc[1][tn], 0, 0, 0);
                }
            }
        }
    }

    if (wave < 4) {
        // kq: m = (2w+T)*16+qq*4+r, pos = n0+tn*16+c_l; scaled+biased -> kqh
#pragma unroll
        for (int T = 0; T < 2; ++T) {
            const int m0 = (2 * wave + T) * 16 + qq * 4;
            const float4 bq = *(const float4*)&bkq[m0];
            const int rowoff = ((2 * wave + T) * 2 + (qq >> 1)) * 128 + c_l * 8 + (qq & 1) * 4;
#pragma unroll
            for (int tn = 0; tn < 8; ++tn) {
                const float v0 = (acc[T][tn][0] + bq.x) * SCALE_S;
                const float v1 = (acc[T][tn][1] + bq.y) * SCALE_S;
                const float v2 = (acc[T][tn][2] + bq.z) * SCALE_S;
                const float v3 = (acc[T][tn][3] + bq.w) * SCALE_S;
                *(uint2*)(kqh + b * 524288 + ((n0 >> 4) + tn) * 2048 + rowoff) = pk4h(v0, v1, v2, v3);
            }
        }
    } else {
        const int w4 = wave - 4;
        // v^T: pos = n0+(2w4+T)*16+qq*4+r, vd = tn*16+c_l -> vsw
#pragma unroll
        for (int T = 0; T < 2; ++T) {
            const int posq = n0 + (2 * w4 + T) * 16 + qq * 4;
#pragma unroll
            for (int tn = 0; tn < 8; ++tn) {
                const float bias = bv[tn * 16 + c_l];
                *(uint2*)(vsw + b * 524288 + tn * 65536 + (posq >> 3) * 128 + c_l * 8 + (posq & 7)) =
                    pk4h(acc[T][tn][0] + bias, acc[T][tn][1] + bias,
                         acc[T][tn][2] + bias, acc[T][tn][3] + bias);
            }
        }
    }
}

// ---------------------------------------------------------------------------
// Kernel 2: flash attention. BM=128, BN=64, D=128. 8 waves = 4 mw x 2 nw.
// Wave: 32 q-rows (2 colsets), 32-key half, full vd=128, local online softmax.
// S^T = K·Q^T (A=K from LDS reused x2, B=Q regs); P via b64/b128 LDS;
// O^T = V·P (A=V, B=P). Epilogue: merge (m,l,O) across nw pair via LDS.
// ---------------------------------------------------------------------------
__global__ __launch_bounds__(512, 2) void flash_kernel(
    const u16* __restrict__ kqh, const u16* __restrict__ vsw,
    u16* __restrict__ ctxh)
{
    // u16: K0 [0,8192) K1 [8192,16384) V [16384,24576) P [24576,32768)
    __shared__ __align__(16) u16 lds[32768];
    const int b  = blockIdx.x & 7;
    const int mt = blockIdx.x >> 3;
    const int t  = threadIdx.x;
    const int wave = t >> 6, lane = t & 63;
    const int qq = lane >> 4, c_l = lane & 15;
    const int mw = wave >> 1, nw = wave & 1;
    const int pbase = 24576 + wave * 1024;
    const u16* kqb = kqh + b * 524288;
    const u16* vb  = vsw + b * 524288;

    // Q B-frags in regs: [cs][ks]
    half8 q[2][4];
#pragma unroll
    for (int cs = 0; cs < 2; ++cs)
#pragma unroll
        for (int ks = 0; ks < 4; ++ks)
            q[cs][ks] = *(const half8*)(kqb + (mt * 8 + mw * 2 + cs) * 2048 + ks * 512 + lane * 8);

    f32x4 o[8][2];
#pragma unroll
    for (int vt = 0; vt < 8; ++vt)
#pragma unroll
        for (int cs = 0; cs < 2; ++cs) o[vt][cs] = (f32x4){0.f, 0.f, 0.f, 0.f};
    float m_s[2] = {-__builtin_inff(), -__builtin_inff()};
    float l_s[2] = {0.f, 0.f};

    // preload K(0)
#pragma unroll
    for (int ch = 0; ch < 2; ++ch) {
        const int c = wave * 2 + ch;
        dma16(kqb + c * 512 + lane * 8, &lds[c * 512]);
    }

    for (int it = 0; it < 64; ++it) {
        const int n0 = it << 6;
        const int kc = (it & 1) << 13;
        __syncthreads();                               // A: K(it) ready, V free
#pragma unroll
        for (int ch = 0; ch < 2; ++ch) {               // V(it): 16 chunks
            const int cc = wave * 2 + ch;
            dma16(vb + (cc >> 1) * 65536 + (n0 >> 3) * 128 + (cc & 1) * 512 + lane * 8,
                  &lds[16384 + cc * 512]);
        }
        if (it < 63) {
#pragma unroll
            for (int ch = 0; ch < 2; ++ch) {           // K(it+1) prefetch
                const int c = wave * 2 + ch;
                dma16(kqb + ((n0 + 64) >> 4) * 2048 + c * 512 + lane * 8,
                      &lds[(kc ^ 8192) + c * 512]);
            }
        }

        // S^T = K·Q^T : rows n (wave's 32-key half), cols m (32 q-rows)
        f32x4 s[2][2];
#pragma unroll
        for (int nrs = 0; nrs < 2; ++nrs)
#pragma unroll
            for (int cs = 0; cs < 2; ++cs) s[nrs][cs] = (f32x4){0.f, 0.f, 0.f, 0.f};
#pragma unroll
        for (int nrs = 0; nrs < 2; ++nrs) {
#pragma unroll
            for (int ks = 0; ks < 4; ++ks) {
                const half8 kf = *(const half8*)&lds[kc + (nw * 2 + nrs) * 2048 + ks * 512 + lane * 8];
                s[nrs][0] = __builtin_amdgcn_mfma_f32_16x16x32_f16(kf, q[0][ks], s[nrs][0], 0, 0, 0);
                s[nrs][1] = __builtin_amdgcn_mfma_f32_16x16x32_f16(kf, q[1][ks], s[nrs][1], 0, 0, 0);
            }
        }

        // local online softmax (base-2); lane state is for column m = cs*16+c_l
        float al[2];
#pragma unroll
        for (int cs = 0; cs < 2; ++cs) {
            float mx = fmaxf(fmaxf(fmaxf(s[0][cs][0], s[0][cs][1]), fmaxf(s[0][cs][2], s[0][cs][3])),
                             fmaxf(fmaxf(s[1][cs][0], s[1][cs][1]), fmaxf(s[1][cs][2], s[1][cs][3])));
            mx = fmaxf(mx, __shfl_xor(mx, 16, 64));
            mx = fmaxf(mx, __shfl_xor(mx, 32, 64));
            const float mn = fmaxf(m_s[cs], mx);
            al[cs] = __builtin_amdgcn_exp2f(m_s[cs] - mn);
            m_s[cs] = mn;
            float ps = 0.f;
#pragma unroll
            for (int nrs = 0; nrs < 2; ++nrs) {
                const float p0 = __builtin_amdgcn_exp2f(s[nrs][cs][0] - mn);
                const float p1 = __builtin_amdgcn_exp2f(s[nrs][cs][1] - mn);
                const float p2 = __builtin_amdgcn_exp2f(s[nrs][cs][2] - mn);
                const float p3 = __builtin_amdgcn_exp2f(s[nrs][cs][3] - mn);
                ps += (p0 + p1) + (p2 + p3);
                *(uint2*)&lds[pbase + cs * 512 + (nrs * 2 + (qq >> 1)) * 128 + c_l * 8 + (qq & 1) * 4] =
                    pk4h(p0, p1, p2, p3);
            }
            l_s[cs] = l_s[cs] * al[cs] + ps;
        }
        if (__any(al[0] < 1.f || al[1] < 1.f)) {
#pragma unroll
            for (int vt = 0; vt < 8; ++vt) {
                o[vt][0] *= al[0];
                o[vt][1] *= al[1];
            }
        }

        __syncthreads();                               // B: V(it) ready
        const half8 pf0 = *(const half8*)&lds[pbase + lane * 8];
        const half8 pf1 = *(const half8*)&lds[pbase + 512 + lane * 8];
#pragma unroll
        for (int vt = 0; vt < 8; ++vt) {
            const half8 vf = *(const half8*)&lds[16384 + vt * 1024 + nw * 512 + lane * 8];
            o[vt][0] = __builtin_amdgcn_mfma_f32_16x16x32_f16(vf, pf0, o[vt][0], 0, 0, 0);
            o[vt][1] = __builtin_amdgcn_mfma_f32_16x16x32_f16(vf, pf1, o[vt][1], 0, 0, 0);
        }
    }

    // ---- epilogue: merge the nw pair ----
#pragma unroll
    for (int cs = 0; cs < 2; ++cs) {
        l_s[cs] += __shfl_xor(l_s[cs], 16, 64);
        l_s[cs] += __shfl_xor(l_s[cs], 32, 64);
    }
    __syncthreads();
    float* mlf = (float*)&lds[24576];
    if (qq == 0) {
#pragma unroll
        for (int cs = 0; cs < 2; ++cs) {
            mlf[((mw * 2 + nw) * 2 + cs) * 32 + c_l * 2]     = m_s[cs];
            mlf[((mw * 2 + nw) * 2 + cs) * 32 + c_l * 2 + 1] = l_s[cs];
        }
    }
    __syncthreads();
    float ga[2], inv[2];
#pragma unroll
    for (int cs = 0; cs < 2; ++cs) {
        const int base = ((mw * 2 + (nw ^ 1)) * 2 + cs) * 32 + c_l * 2;
        const float m2 = mlf[base], l2 = mlf[base + 1];
        const float ms = fmaxf(m_s[cs], m2);
        const float g1 = __builtin_amdgcn_exp2f(m_s[cs] - ms);
        const float g2 = __builtin_amdgcn_exp2f(m2 - ms);
        ga[cs] = g1;
        inv[cs] = 1.f / (l_s[cs] * g1 + l2 * g2);
    }
    __syncthreads();                                    // ml reads done before obuf reuse
    float* obuf = (float*)lds;                          // 16K floats, region mw*4096
    if (nw == 1) {
#pragma unroll
        for (int vt = 0; vt < 8; ++vt)
#pragma unroll
            for (int cs = 0; cs < 2; ++cs)
                *(f32x4*)&obuf[mw * 4096 + ((vt * 2 + cs) * 64 + lane) * 4] = o[vt][cs] * ga[cs];
    }
    __syncthreads();
    if (nw == 0) {
        u16* cb = ctxh + b * 524288;
#pragma unroll
        for (int vt = 0; vt < 8; ++vt) {
#pragma unroll
            for (int cs = 0; cs < 2; ++cs) {
                const f32x4 op = *(const f32x4*)&obuf[mw * 4096 + ((vt * 2 + cs) * 64 + lane) * 4];
                const f32x4 oo = (o[vt][cs] * ga[cs] + op) * inv[cs];
                // pos = mt*128+mw*32+cs*16+c_l ; vd = vt*16+qq*4+r
                *(uint2*)(cb + (mt * 8 + mw * 2 + cs) * 2048 + (vt * 2 + (qq >> 1)) * 128 +
                          c_l * 8 + (qq & 1) * 4) = pk4h(oo[0], oo[1], oo[2], oo[3]);
            }
        }
    }
}

// ---------------------------------------------------------------------------
// Kernel 3: out = w_o @ ctx + b_o (fp32). Single-term fp16. M=256 x N=128, K=128.
// ---------------------------------------------------------------------------
__global__ __launch_bounds__(512, 2) void out_kernel(
    const u16* __restrict__ woh, const u16* __restrict__ ctxh,
    const float* __restrict__ bo, float* __restrict__ out)
{
    __shared__ __align__(16) u16 lds[24576];   // A(wo) 16384 | B(ctx) 8192
    const int b  = blockIdx.x & 7;
    const int nb = blockIdx.x >> 3;
    const int n0 = nb << 7;
    const int t  = threadIdx.x;
    const int wave = t >> 6, lane = t & 63;
    const int qq = lane >> 4, c_l = lane & 15;

    f32x4 acc[2][8];
#pragma unroll
    for (int i = 0; i < 2; ++i)
#pragma unroll
        for (int j = 0; j < 8; ++j) acc[i][j] = (f32x4){0.f, 0.f, 0.f, 0.f};

    for (int ki = 0; ki < 2; ++ki) {
        __syncthreads();
#pragma unroll
        for (int ch = 0; ch < 6; ++ch) {
            const int c = wave * 6 + ch;               // 0..47
            if (c < 32) {
                dma16(woh + (c >> 1) * 2048 + ki * 1024 + (c & 1) * 512 + lane * 8,
                      &lds[c * 512]);
            } else {
                const int cc = c - 32;
                dma16(ctxh + b * 524288 + ((n0 >> 4) + (cc >> 1)) * 2048 + ki * 1024 +
                          (cc & 1) * 512 + lane * 8,
                      &lds[16384 + cc * 512]);
            }
        }
        __syncthreads();
#pragma unroll
        for (int ks = 0; ks < 2; ++ks) {
            const half8 a0 = *(const half8*)&lds[(2 * wave) * 1024 + ks * 512 + lane * 8];
            const half8 a1 = *(const half8*)&lds[(2 * wave + 1) * 1024 + ks * 512 + lane * 8];
#pragma unroll
            for (int tn = 0; tn < 8; ++tn) {
                const half8 bf = *(const half8*)&lds[16384 + tn * 1024 + ks * 512 + lane * 8];
                acc[0][tn] = __builtin_amdgcn_mfma_f32_16x16x32_f16(a0, bf, acc[0][tn], 0, 0, 0);
                acc[1][tn] = __builtin_amdgcn_mfma_f32_16x16x32_f16(a1, bf, acc[1][tn], 0, 0, 0);
            }
        }
    }

#pragma unroll
    for (int T = 0; T < 2; ++T) {
        const int m0 = (2 * wave + T) * 16 + qq * 4;
        const float4 bq = *(const float4*)&bo[m0];
#pragma unroll
        for (int tn = 0; tn < 8; ++tn) {
            const int pos = n0 + tn * 16 + c_l;
            out[(size_t)((b * 256 + m0 + 0) * NN) + pos] = acc[T][tn][0] + bq.x;
            out[(size_t)((b * 256 + m0 + 1) * NN) + pos] = acc[T][tn][1] + bq.y;
            out[(size_t)((b * 256 + m0 + 2) * NN) + pos] = acc[T][tn][2] + bq.z;
            out[(size_t)((b * 256 + m0 + 3) * NN) + pos] = acc[T][tn][3] + bq.w;
        }
    }
}

// ---------------------------------------------------------------------------
extern "C" void kernel_launch(void* const* d_in, const int* in_sizes, int n_in,
                              void* d_out, int out_size, void* d_ws, size_t ws_size,
                              hipStream_t stream) {
    const float* x    = (const float*)d_in[0];
    const float* w_kq = (const float*)d_in[1];
    const float* b_kq = (const float*)d_in[2];
    const float* w_v  = (const float*)d_in[3];
    const float* b_v  = (const float*)d_in[4];
    const float* w_o  = (const float*)d_in[5];
    const float* b_o  = (const float*)d_in[6];
    float* out = (float*)d_out;

    // ws: kqh 8MB | vsw 8MB | ctxh 8MB | wA 128KB | woh 64KB
    u16* kqh  = (u16*)d_ws;
    u16* vsw  = (u16*)((char*)d_ws + (8u << 20));
    u16* ctxh = (u16*)((char*)d_ws + (16u << 20));
    u16* wA   = (u16*)((char*)d_ws + (24u << 20));
    u16* woh  = wA + 65536;

    wcast_kernel<<<dim3(48), dim3(256), 0, stream>>>(w_kq, w_v, w_o, wA, woh);
    kqv_kernel<<<dim3(256), dim3(512), 0, stream>>>(x, wA, b_kq, b_v, kqh, vsw);
    flash_kernel<<<dim3(256), dim3(512), 0, stream>>>(kqh, vsw, ctxh);
    out_kernel<<<dim3(256), dim3(512), 0, stream>>>(woh, ctxh, b_o, out);
}